// Round 1
// baseline (4500.280 us; speedup 1.0000x reference)
//
#include <hip/hip_runtime.h>
#include <hip/hip_bf16.h>
#include <hip/hip_cooperative_groups.h>
#include <stdint.h>

namespace cg = cooperative_groups;

#define HH   512
#define VV   32000
#define T1N  128
#define T2N  64
#define BB   32

typedef __attribute__((ext_vector_type(8))) short short8;
typedef __attribute__((ext_vector_type(4))) float f32x4;

__device__ __forceinline__ ushort f2b(float f) {
  unsigned u = __float_as_uint(f);
  unsigned r = (u + 0x7fffu + ((u >> 16) & 1u)) >> 16;
  return (ushort)r;
}
__device__ __forceinline__ float blo(unsigned u){ return __uint_as_float(u << 16); }
__device__ __forceinline__ float bhi(unsigned u){ return __uint_as_float(u & 0xffff0000u); }

__device__ __forceinline__ float fast_tanh(float x) {
  float ax = fabsf(x);
  float e  = __expf(-2.f * ax);
  float t  = (1.f - e) / (1.f + e);
  return x < 0.f ? -t : t;
}
__device__ __forceinline__ float fsig(float x) { return 1.f / (1.f + __expf(-x)); }

// ---------------- conversions ----------------
__global__ __launch_bounds__(256) void k_cvt(const float* __restrict__ s, ushort* __restrict__ d, int n) {
  int i = (blockIdx.x * 256 + threadIdx.x) * 4;
  if (i < n) {
    float4 v = *(const float4*)(s + i);
    ushort4 o = { f2b(v.x), f2b(v.y), f2b(v.z), f2b(v.w) };
    *(ushort4*)(d + i) = o;
  }
}

// wa_W (512,1024) -> WxB = wa_W[:, :512], WeB = wa_W[:, 512:]
__global__ __launch_bounds__(256) void k_cvt_wa(const float* __restrict__ wa,
                                                ushort* __restrict__ Wx, ushort* __restrict__ We) {
  int i = (blockIdx.x * 256 + threadIdx.x) * 4;
  int half = (i >= HH * HH);
  int j = i & (HH * HH - 1);
  int o = j >> 9, c = j & 511;
  const float* s = wa + (size_t)o * 1024 + c + (half ? 512 : 0);
  float4 v = *(const float4*)s;
  ushort4 ov = { f2b(v.x), f2b(v.y), f2b(v.z), f2b(v.w) };
  *(ushort4*)((half ? We : Wx) + j) = ov;
}

// x = emb[toks] -> bf16 into ginB[:, 0:512] (row stride 1024)
__global__ __launch_bounds__(256) void k_embed(const int* __restrict__ toks, const float* __restrict__ emb,
                                               ushort* __restrict__ ginB) {
  int i = (blockIdx.x * 256 + threadIdx.x) * 4;
  int row = i >> 9, c = i & 511;
  int tok = toks[row];
  float4 v = *(const float4*)(emb + (size_t)tok * HH + c);
  ushort4 ov = { f2b(v.x), f2b(v.y), f2b(v.z), f2b(v.w) };
  *(ushort4*)(ginB + (size_t)row * 1024 + c) = ov;
}

// ---------------- bf16 MFMA GEMM (fp32 out) ----------------
__global__ __launch_bounds__(256) void k_gemm(const ushort* __restrict__ A, int lda,
                                              const ushort* __restrict__ B,
                                              const float* __restrict__ bias,
                                              float* __restrict__ C, int ldc, int K) {
  __shared__ ushort sA[128 * 32];
  __shared__ ushort sB[128 * 32];
  const int tid  = threadIdx.x;
  const int bm   = blockIdx.y * 128;
  const int bn   = blockIdx.x * 128;
  const int lane = tid & 63;
  const int wave = tid >> 6;
  const int wm   = (wave >> 1) * 64;
  const int wn   = (wave & 1) * 64;
  const int m16  = lane & 15;
  const int quad = lane >> 4;

  f32x4 acc[4][4] = {};

  for (int k0 = 0; k0 < K; k0 += 32) {
#pragma unroll
    for (int q = 0; q < 2; ++q) {
      int idx = q * 256 + tid;
      int row = idx >> 2;
      int kc  = (idx & 3) << 3;
      uint4 va = *(const uint4*)(A + (size_t)(bm + row) * lda + k0 + kc);
      *(uint4*)(&sA[idx * 8]) = va;
      uint4 vb = *(const uint4*)(B + (size_t)(bn + row) * K + k0 + kc);
      *(uint4*)(&sB[idx * 8]) = vb;
    }
    __syncthreads();
    short8 a[4], b[4];
#pragma unroll
    for (int i = 0; i < 4; ++i)
      a[i] = *(const short8*)(&sA[(wm + i * 16 + m16) * 32 + quad * 8]);
#pragma unroll
    for (int j = 0; j < 4; ++j)
      b[j] = *(const short8*)(&sB[(wn + j * 16 + m16) * 32 + quad * 8]);
#pragma unroll
    for (int i = 0; i < 4; ++i)
#pragma unroll
      for (int j = 0; j < 4; ++j)
        acc[i][j] = __builtin_amdgcn_mfma_f32_16x16x32_bf16(a[i], b[j], acc[i][j], 0, 0, 0);
    __syncthreads();
  }
#pragma unroll
  for (int i = 0; i < 4; ++i) {
    int gm = bm + wm + i * 16 + quad * 4;
#pragma unroll
    for (int j = 0; j < 4; ++j) {
      int gn = bn + wn + j * 16 + m16;
      float bv = bias ? bias[gn] : 0.f;
#pragma unroll
      for (int r = 0; r < 4; ++r)
        C[(size_t)(gm + r) * ldc + gn] = acc[i][j][r] + bv;
    }
  }
}

// same GEMM but bf16 output (for gi0)
__global__ __launch_bounds__(256) void k_gemm_b16(const ushort* __restrict__ A, int lda,
                                                  const ushort* __restrict__ B,
                                                  const float* __restrict__ bias,
                                                  ushort* __restrict__ C, int ldc, int K) {
  __shared__ ushort sA[128 * 32];
  __shared__ ushort sB[128 * 32];
  const int tid  = threadIdx.x;
  const int bm   = blockIdx.y * 128;
  const int bn   = blockIdx.x * 128;
  const int lane = tid & 63;
  const int wave = tid >> 6;
  const int wm   = (wave >> 1) * 64;
  const int wn   = (wave & 1) * 64;
  const int m16  = lane & 15;
  const int quad = lane >> 4;

  f32x4 acc[4][4] = {};

  for (int k0 = 0; k0 < K; k0 += 32) {
#pragma unroll
    for (int q = 0; q < 2; ++q) {
      int idx = q * 256 + tid;
      int row = idx >> 2;
      int kc  = (idx & 3) << 3;
      uint4 va = *(const uint4*)(A + (size_t)(bm + row) * lda + k0 + kc);
      *(uint4*)(&sA[idx * 8]) = va;
      uint4 vb = *(const uint4*)(B + (size_t)(bn + row) * K + k0 + kc);
      *(uint4*)(&sB[idx * 8]) = vb;
    }
    __syncthreads();
    short8 a[4], b[4];
#pragma unroll
    for (int i = 0; i < 4; ++i)
      a[i] = *(const short8*)(&sA[(wm + i * 16 + m16) * 32 + quad * 8]);
#pragma unroll
    for (int j = 0; j < 4; ++j)
      b[j] = *(const short8*)(&sB[(wn + j * 16 + m16) * 32 + quad * 8]);
#pragma unroll
    for (int i = 0; i < 4; ++i)
#pragma unroll
      for (int j = 0; j < 4; ++j)
        acc[i][j] = __builtin_amdgcn_mfma_f32_16x16x32_bf16(a[i], b[j], acc[i][j], 0, 0, 0);
    __syncthreads();
  }
#pragma unroll
  for (int i = 0; i < 4; ++i) {
    int gm = bm + wm + i * 16 + quad * 4;
#pragma unroll
    for (int j = 0; j < 4; ++j) {
      int gn = bn + wn + j * 16 + m16;
      float bv = bias ? bias[gn] : 0.f;
#pragma unroll
      for (int r = 0; r < 4; ++r)
        C[(size_t)(gm + r) * ldc + gn] = f2b(acc[i][j][r] + bv);
    }
  }
}

// ---------------- attention ----------------
__global__ __launch_bounds__(256) void k_scores(const float* __restrict__ xproj,
                                                const float* __restrict__ encp,
                                                const float* __restrict__ vaW,
                                                float* __restrict__ e) {
  int t2g = blockIdx.x >> 5;
  int b   = blockIdx.x & 31;
  __shared__ float sx[4][512];
  int tid = threadIdx.x;
  for (int i = tid; i < 4 * 512; i += 256) {
    int tt = i >> 9, h = i & 511;
    sx[tt][h] = xproj[((size_t)(t2g * 4 + tt) * BB + b) * HH + h];
  }
  __syncthreads();
  int lane = tid & 63, w = tid >> 6;
  int h8 = lane * 8;
  float va[8];
#pragma unroll
  for (int j = 0; j < 8; ++j) va[j] = vaW[h8 + j];
  for (int t1 = w; t1 < T1N; t1 += 4) {
    const float* ep = encp + ((size_t)t1 * BB + b) * HH + h8;
    float ev[8];
    *(float4*)&ev[0] = *(const float4*)ep;
    *(float4*)&ev[4] = *(const float4*)(ep + 4);
    float s0 = 0, s1 = 0, s2 = 0, s3 = 0;
#pragma unroll
    for (int j = 0; j < 8; ++j) {
      float epj = ev[j], vj = va[j];
      s0 += fast_tanh(sx[0][h8 + j] + epj) * vj;
      s1 += fast_tanh(sx[1][h8 + j] + epj) * vj;
      s2 += fast_tanh(sx[2][h8 + j] + epj) * vj;
      s3 += fast_tanh(sx[3][h8 + j] + epj) * vj;
    }
#pragma unroll
    for (int off = 32; off; off >>= 1) {
      s0 += __shfl_down(s0, off);
      s1 += __shfl_down(s1, off);
      s2 += __shfl_down(s2, off);
      s3 += __shfl_down(s3, off);
    }
    if (lane == 0) {
      size_t base = ((size_t)(t2g * 4) * BB + b) * T1N + t1;
      e[base]                 = s0;
      e[base + 1 * BB * T1N]  = s1;
      e[base + 2 * BB * T1N]  = s2;
      e[base + 3 * BB * T1N]  = s3;
    }
  }
}

__global__ __launch_bounds__(128) void k_softmax(const float* __restrict__ e, float* __restrict__ score,
                                                 float* __restrict__ out_last) {
  int row = blockIdx.x;
  int tid = threadIdx.x;
  float v = e[(size_t)row * T1N + tid];
  __shared__ float red[128];
  red[tid] = v; __syncthreads();
  for (int s = 64; s; s >>= 1) { if (tid < s) red[tid] = fmaxf(red[tid], red[tid + s]); __syncthreads(); }
  float mx = red[0]; __syncthreads();
  float p = __expf(v - mx);
  red[tid] = p; __syncthreads();
  for (int s = 64; s; s >>= 1) { if (tid < s) red[tid] += red[tid + s]; __syncthreads(); }
  float sc = p / red[0];
  score[(size_t)row * T1N + tid] = sc;
  if ((row >> 5) == T2N - 1) out_last[tid * BB + (row & 31)] = sc;
}

__global__ __launch_bounds__(256) void k_attv(const float* __restrict__ enc, const float* __restrict__ score,
                                              ushort* __restrict__ ginB) {
  int t2g = blockIdx.x >> 5;
  int b   = blockIdx.x & 31;
  __shared__ float ssc[8][T1N];
  int tid = threadIdx.x;
  for (int i = tid; i < 8 * T1N; i += 256) {
    int j = i >> 7, t1 = i & 127;
    ssc[j][t1] = score[((size_t)(t2g * 8 + j) * BB + b) * T1N + t1];
  }
  __syncthreads();
  float a0[8] = {}, a1[8] = {};
  for (int t1 = 0; t1 < T1N; ++t1) {
    const float* er = enc + ((size_t)t1 * BB + b) * HH;
    float e0 = er[tid], e1 = er[tid + 256];
#pragma unroll
    for (int j = 0; j < 8; ++j) { a0[j] += e0 * ssc[j][t1]; a1[j] += e1 * ssc[j][t1]; }
  }
#pragma unroll
  for (int j = 0; j < 8; ++j) {
    size_t r = (size_t)(t2g * 8 + j) * BB + b;
    ginB[r * 1024 + 512 + tid]       = f2b(a0[j]);
    ginB[r * 1024 + 512 + tid + 256] = f2b(a1[j]);
  }
}

// ---------------- persistent cooperative recurrence ----------------
// GRU elementwise pair helper
__device__ __forceinline__ void gru_pair(uint gr, uint gz, uint gn, uint hr, uint hz, uint hn,
                                         float hold0, float hold1, float& o0, float& o1) {
  float r0 = fsig(blo(gr) + blo(hr));
  float r1 = fsig(bhi(gr) + bhi(hr));
  float z0 = fsig(blo(gz) + blo(hz));
  float z1 = fsig(bhi(gz) + bhi(hz));
  float n0 = fast_tanh(blo(gn) + r0 * blo(hn));
  float n1 = fast_tanh(bhi(gn) + r1 * bhi(hn));
  o0 = (1.f - z0) * n0 + z0 * hold0;
  o1 = (1.f - z1) * n1 + z1 * hold1;
}

struct RecurP {
  const ushort* Whh0B; const ushort* Whh1B; const ushort* Wih1B;
  const float* bhh0; const float* bhh1; const float* bih1;
  const ushort* gi0B;
  const float* state;     // (2,B,H) fp32
  const ushort* stateB;   // bf16 h0 init
  ushort* gh0x;
  ushort* gh1b0; ushort* gh1b1;
  ushort* gi1x;
  float* h0b0; float* h0b1;
  float* h1b0; float* h1b1;
  ushort* h0B0; ushort* h0B1;
  float* h_out;           // d_out h section (2,B,H)
  ushort* ysB;            // (T2N,B,H) bf16
};

// One launch replaces 64 x (stepA, stepB) + final: 128 grid syncs instead of
// 129 kernel launches. 48 blocks (<=256 CUs, 33 KB LDS -> trivially co-resident).
// Bodies are verbatim ports of k_stepA / k_stepB / k_final.
__global__ __launch_bounds__(256, 1) void k_recur(RecurP p) {
  cg::grid_group grid = cg::this_grid();
  __shared__ ushort sH[32 * 520];
  const int tid  = threadIdx.x;
  const int blk  = blockIdx.x;
  const int lane = tid & 63, wave = tid >> 6;
  const int bt = wave & 1, nt = wave >> 1;
  const int m16 = lane & 15, quad = lane >> 4;
  const int nrow = blk * 32 + nt * 16 + m16;
  const int k0 = tid * 2;
  const float* state1 = p.state + BB * HH;

  const float bv0 = p.bhh0[nrow];
  const float bv1 = p.bhh1[nrow];
  const float bvi = p.bih1[nrow];
  const int brow = bt * 16 + quad * 4;

#pragma unroll 1
  for (int t = 0; t < T2N; ++t) {
    const int par = t & 1;
    // ---------------- phase A (was k_stepA) ----------------
    if (t == 0) {
      for (int i = tid; i < 16384; i += 256) {
        int b = i >> 9, k = i & 511;
        sH[b * 520 + k] = f2b(state1[i]);
      }
    } else {
      const ushort* gh1in = par ? p.gh1b0 : p.gh1b1;              // gh1buf[(t+1)&1]
      const float*  h1in  = (t <= 1) ? state1 : (par ? p.h1b1 : p.h1b0); // h1buf[t&1]
      float*        h1out = par ? p.h1b0 : p.h1b1;                // h1buf[(t+1)&1]
      ushort*       ysprev = p.ysB + (size_t)(t - 1) * BB * HH;
#pragma unroll 4
      for (int b = 0; b < 32; ++b) {
        const ushort* gi = p.gi1x + b * 1536 + k0;
        const ushort* gh = gh1in + b * 1536 + k0;
        uint gir = *(const uint*)(gi);
        uint giz = *(const uint*)(gi + 512);
        uint gin = *(const uint*)(gi + 1024);
        uint hr  = *(const uint*)(gh);
        uint hz  = *(const uint*)(gh + 512);
        uint hn  = *(const uint*)(gh + 1024);
        float2 hold = *(const float2*)(h1in + b * 512 + k0);
        float o0, o1;
        gru_pair(gir, giz, gin, hr, hz, hn, hold.x, hold.y, o0, o1);
        uint hb = (uint)f2b(o0) | ((uint)f2b(o1) << 16);
        *(uint*)(&sH[b * 520 + k0]) = hb;
        if (blk == b) {
          *(float2*)(h1out + b * 512 + k0) = make_float2(o0, o1);
          *(uint*)(ysprev + b * 512 + k0) = hb;
        }
      }
    }
    __syncthreads();

    {
      const ushort* h0Bin = (t == 0) ? p.stateB : (par ? p.h0B0 : p.h0B1); // h0bufB[(t+1)&1]
      ushort* gh1out = par ? p.gh1b1 : p.gh1b0;                            // gh1buf[t&1]
      f32x4 acc0 = {0.f, 0.f, 0.f, 0.f}, acc1 = {0.f, 0.f, 0.f, 0.f};
      const ushort* Arow0  = h0Bin + (bt * 16 + m16) * 512 + quad * 8;
      const ushort* Brow0  = p.Whh0B + (size_t)nrow * 512 + quad * 8;
      const ushort* Brow1  = p.Whh1B + (size_t)nrow * 512 + quad * 8;
      const ushort* sArow1 = &sH[(bt * 16 + m16) * 520 + quad * 8];
#pragma unroll 4
      for (int kc = 0; kc < 16; ++kc) {
        short8 a0 = *(const short8*)(Arow0 + kc * 32);
        short8 b0 = *(const short8*)(Brow0 + kc * 32);
        acc0 = __builtin_amdgcn_mfma_f32_16x16x32_bf16(a0, b0, acc0, 0, 0, 0);
        short8 a1 = *(const short8*)(sArow1 + kc * 32);
        short8 b1 = *(const short8*)(Brow1 + kc * 32);
        acc1 = __builtin_amdgcn_mfma_f32_16x16x32_bf16(a1, b1, acc1, 0, 0, 0);
      }
#pragma unroll
      for (int r = 0; r < 4; ++r) {
        p.gh0x[(brow + r) * 1536 + nrow] = f2b(acc0[r] + bv0);
        gh1out[(brow + r) * 1536 + nrow] = f2b(acc1[r] + bv1);
      }
    }
    grid.sync();

    // ---------------- phase B (was k_stepB) ----------------
    {
      const ushort* gi0t  = p.gi0B + (size_t)t * 32 * 1536;
      const float*  h0in  = (t == 0) ? p.state : (par ? p.h0b0 : p.h0b1); // h0buf[(t+1)&1]
      float*        h0out = par ? p.h0b1 : p.h0b0;                        // h0buf[t&1]
      ushort*       h0Bout = par ? p.h0B1 : p.h0B0;                       // h0bufB[t&1]
#pragma unroll 4
      for (int b = 0; b < 32; ++b) {
        const ushort* gi = gi0t + b * 1536 + k0;
        const ushort* gh = p.gh0x + b * 1536 + k0;
        uint gir = *(const uint*)(gi);
        uint giz = *(const uint*)(gi + 512);
        uint gin = *(const uint*)(gi + 1024);
        uint hr  = *(const uint*)(gh);
        uint hz  = *(const uint*)(gh + 512);
        uint hn  = *(const uint*)(gh + 1024);
        float2 hold = *(const float2*)(h0in + b * 512 + k0);
        float o0, o1;
        gru_pair(gir, giz, gin, hr, hz, hn, hold.x, hold.y, o0, o1);
        uint hb = (uint)f2b(o0) | ((uint)f2b(o1) << 16);
        *(uint*)(&sH[b * 520 + k0]) = hb;
        if (blk == b) {
          *(float2*)(h0out + b * 512 + k0) = make_float2(o0, o1);
          *(uint*)(h0Bout + b * 512 + k0) = hb;
        }
      }
      __syncthreads();

      f32x4 acc = {0.f, 0.f, 0.f, 0.f};
      const ushort* Brow  = p.Wih1B + (size_t)nrow * 512 + quad * 8;
      const ushort* sArow = &sH[(bt * 16 + m16) * 520 + quad * 8];
#pragma unroll 4
      for (int kc = 0; kc < 16; ++kc) {
        short8 a = *(const short8*)(sArow + kc * 32);
        short8 b = *(const short8*)(Brow + kc * 32);
        acc = __builtin_amdgcn_mfma_f32_16x16x32_bf16(a, b, acc, 0, 0, 0);
      }
#pragma unroll
      for (int r = 0; r < 4; ++r)
        p.gi1x[(brow + r) * 1536 + nrow] = f2b(acc[r] + bvi);
    }
    grid.sync();
  }

  // ---------------- final (was k_final): h1(63), ys[63], out_h ----------------
  if (blk < 32) {
    const int b = blk;
    const ushort* gi = p.gi1x + b * 1536 + k0;
    const ushort* gh = p.gh1b1 + b * 1536 + k0;   // gh1buf[63&1] = gh1buf[1]
    uint gir = *(const uint*)(gi);
    uint giz = *(const uint*)(gi + 512);
    uint gin = *(const uint*)(gi + 1024);
    uint hr  = *(const uint*)(gh);
    uint hz  = *(const uint*)(gh + 512);
    uint hn  = *(const uint*)(gh + 1024);
    float2 hold = *(const float2*)(p.h1b0 + b * 512 + k0);  // h1buf[(63+1)&1] = h1(62)
    float o0, o1;
    gru_pair(gir, giz, gin, hr, hz, hn, hold.x, hold.y, o0, o1);
    *(uint*)(p.ysB + (size_t)63 * BB * HH + b * 512 + k0) = (uint)f2b(o0) | ((uint)f2b(o1) << 16);
    p.h_out[16384 + b * 512 + k0]     = o0;
    p.h_out[16384 + b * 512 + k0 + 1] = o1;
    float2 h0p = *(const float2*)(p.h0b1 + b * 512 + k0);   // h0buf[63&1] = h0(63)
    *(float2*)(p.h_out + b * 512 + k0) = h0p;
  }
}

// ---------------- launch ----------------
extern "C" void kernel_launch(void* const* d_in, const int* in_sizes, int n_in,
                              void* d_out, int out_size, void* d_ws, size_t ws_size,
                              hipStream_t stream) {
  const int*   toks  = (const int*)d_in[0];
  const float* state = (const float*)d_in[1];
  const float* enc   = (const float*)d_in[2];
  const float* emb   = (const float*)d_in[3];
  const float* wa_W  = (const float*)d_in[4];
  const float* wa_b  = (const float*)d_in[5];
  const float* va    = (const float*)d_in[6];
  const float* b_ih0 = (const float*)d_in[9];
  const float* b_hh0 = (const float*)d_in[10];
  const float* b_ih1 = (const float*)d_in[13];
  const float* b_hh1 = (const float*)d_in[14];
  const float* out_W = (const float*)d_in[15];
  const float* out_b = (const float*)d_in[16];
  const float* W_ih0 = (const float*)d_in[7];
  const float* W_hh0 = (const float*)d_in[8];
  const float* W_ih1 = (const float*)d_in[11];
  const float* W_hh1 = (const float*)d_in[12];

  float* y_out  = (float*)d_out;
  float* h_out  = y_out + (size_t)T2N * BB * VV;
  float* ls_out = h_out + 2 * BB * HH;

  char* ws = (char*)d_ws;
  size_t off = 0;
  auto alloc = [&](size_t bytes) -> void* {
    void* p = ws + off;
    off += (bytes + 255) & ~(size_t)255;
    return p;
  };
  ushort* encB   = (ushort*)alloc((size_t)T1N * BB * HH * 2);
  ushort* ginB   = (ushort*)alloc((size_t)T2N * BB * 2 * HH * 2);
  ushort* WeB    = (ushort*)alloc((size_t)HH * HH * 2);
  ushort* WxB    = (ushort*)alloc((size_t)HH * HH * 2);
  ushort* Wih0B  = (ushort*)alloc((size_t)3 * HH * 2 * HH * 2);
  ushort* Whh0B  = (ushort*)alloc((size_t)3 * HH * HH * 2);
  ushort* Wih1B  = (ushort*)alloc((size_t)3 * HH * HH * 2);
  ushort* Whh1B  = (ushort*)alloc((size_t)3 * HH * HH * 2);
  ushort* outWB  = (ushort*)alloc((size_t)VV * HH * 2);
  ushort* stateB = (ushort*)alloc((size_t)BB * HH * 2);
  float* encproj = (float*)alloc((size_t)T1N * BB * HH * 4);
  float* xproj   = (float*)alloc((size_t)T2N * BB * HH * 4);
  float* eM      = (float*)alloc((size_t)T2N * BB * T1N * 4);
  float* score   = (float*)alloc((size_t)T2N * BB * T1N * 4);
  ushort* gi0B   = (ushort*)alloc((size_t)T2N * BB * 3 * HH * 2);
  ushort* gh0x   = (ushort*)alloc((size_t)BB * 3 * HH * 2);
  ushort* gh1buf0 = (ushort*)alloc((size_t)BB * 3 * HH * 2);
  ushort* gh1buf1 = (ushort*)alloc((size_t)BB * 3 * HH * 2);
  ushort* gi1x   = (ushort*)alloc((size_t)BB * 3 * HH * 2);
  float* h0buf0  = (float*)alloc((size_t)BB * HH * 4);
  float* h0buf1  = (float*)alloc((size_t)BB * HH * 4);
  float* h1buf0  = (float*)alloc((size_t)BB * HH * 4);
  float* h1buf1  = (float*)alloc((size_t)BB * HH * 4);
  ushort* h0bufB0 = (ushort*)alloc((size_t)BB * HH * 2);
  ushort* h0bufB1 = (ushort*)alloc((size_t)BB * HH * 2);
  ushort* ysB    = (ushort*)alloc((size_t)T2N * BB * HH * 2);

  // preamble
  k_cvt<<<VV * HH / 1024, 256, 0, stream>>>(out_W, outWB, VV * HH);
  k_cvt<<<T1N * BB * HH / 1024, 256, 0, stream>>>(enc, encB, T1N * BB * HH);
  k_cvt<<<3 * HH * 2 * HH / 1024, 256, 0, stream>>>(W_ih0, Wih0B, 3 * HH * 2 * HH);
  k_cvt<<<3 * HH * HH / 1024, 256, 0, stream>>>(W_hh0, Whh0B, 3 * HH * HH);
  k_cvt<<<3 * HH * HH / 1024, 256, 0, stream>>>(W_ih1, Wih1B, 3 * HH * HH);
  k_cvt<<<3 * HH * HH / 1024, 256, 0, stream>>>(W_hh1, Whh1B, 3 * HH * HH);
  k_cvt<<<BB * HH / 1024, 256, 0, stream>>>(state, stateB, BB * HH);
  k_cvt_wa<<<2 * HH * HH / 1024, 256, 0, stream>>>(wa_W, WxB, WeB);
  k_embed<<<T2N * BB * HH / 1024, 256, 0, stream>>>(toks, emb, ginB);

  k_gemm<<<dim3(HH / 128, T1N * BB / 128), 256, 0, stream>>>(encB, HH, WeB, wa_b, encproj, HH, HH);
  k_gemm<<<dim3(HH / 128, T2N * BB / 128), 256, 0, stream>>>(ginB, 2 * HH, WxB, nullptr, xproj, HH, HH);

  k_scores<<<512, 256, 0, stream>>>(xproj, encproj, va, eM);
  k_softmax<<<T2N * BB, 128, 0, stream>>>(eM, score, ls_out);
  k_attv<<<256, 256, 0, stream>>>(enc, score, ginB);

  k_gemm_b16<<<dim3(3 * HH / 128, T2N * BB / 128), 256, 0, stream>>>(ginB, 2 * HH, Wih0B, b_ih0, gi0B, 3 * HH, 2 * HH);

  // recurrence: single persistent cooperative kernel (replaces 129 launches)
  RecurP rp;
  rp.Whh0B = Whh0B; rp.Whh1B = Whh1B; rp.Wih1B = Wih1B;
  rp.bhh0 = b_hh0; rp.bhh1 = b_hh1; rp.bih1 = b_ih1;
  rp.gi0B = gi0B;
  rp.state = state; rp.stateB = stateB;
  rp.gh0x = gh0x;
  rp.gh1b0 = gh1buf0; rp.gh1b1 = gh1buf1;
  rp.gi1x = gi1x;
  rp.h0b0 = h0buf0; rp.h0b1 = h0buf1;
  rp.h1b0 = h1buf0; rp.h1b1 = h1buf1;
  rp.h0B0 = h0bufB0; rp.h0B1 = h0bufB1;
  rp.h_out = h_out; rp.ysB = ysB;
  void* kargs[] = { &rp };
  hipLaunchCooperativeKernel((const void*)k_recur, dim3(48), dim3(256), kargs, 0, stream);

  // y = ys @ out_W^T + out_b
  k_gemm<<<dim3(VV / 128, T2N * BB / 128), 256, 0, stream>>>(ysB, HH, outWB, out_b, y_out, VV, HH);
}

// Round 3
// 3798.475 us; speedup vs baseline: 1.1848x; 1.1848x over previous
//
#include <hip/hip_runtime.h>
#include <hip/hip_bf16.h>
#include <stdint.h>

#define HH   512
#define VV   32000
#define T1N  128
#define T2N  64
#define BB   32

typedef __attribute__((ext_vector_type(8))) short short8;
typedef __attribute__((ext_vector_type(4))) float f32x4;

__device__ __forceinline__ ushort f2b(float f) {
  unsigned u = __float_as_uint(f);
  unsigned r = (u + 0x7fffu + ((u >> 16) & 1u)) >> 16;
  return (ushort)r;
}
__device__ __forceinline__ float blo(unsigned u){ return __uint_as_float(u << 16); }
__device__ __forceinline__ float bhi(unsigned u){ return __uint_as_float(u & 0xffff0000u); }

__device__ __forceinline__ float fast_tanh(float x) {
  float ax = fabsf(x);
  float e  = __expf(-2.f * ax);
  float t  = (1.f - e) / (1.f + e);
  return x < 0.f ? -t : t;
}
__device__ __forceinline__ float fsig(float x) { return 1.f / (1.f + __expf(-x)); }

// ---------------- conversions ----------------
__global__ __launch_bounds__(256) void k_cvt(const float* __restrict__ s, ushort* __restrict__ d, int n) {
  int i = (blockIdx.x * 256 + threadIdx.x) * 4;
  if (i < n) {
    float4 v = *(const float4*)(s + i);
    ushort4 o = { f2b(v.x), f2b(v.y), f2b(v.z), f2b(v.w) };
    *(ushort4*)(d + i) = o;
  }
}

// wa_W (512,1024) -> WxB = wa_W[:, :512], WeB = wa_W[:, 512:]
__global__ __launch_bounds__(256) void k_cvt_wa(const float* __restrict__ wa,
                                                ushort* __restrict__ Wx, ushort* __restrict__ We) {
  int i = (blockIdx.x * 256 + threadIdx.x) * 4;
  int half = (i >= HH * HH);
  int j = i & (HH * HH - 1);
  int o = j >> 9, c = j & 511;
  const float* s = wa + (size_t)o * 1024 + c + (half ? 512 : 0);
  float4 v = *(const float4*)s;
  ushort4 ov = { f2b(v.x), f2b(v.y), f2b(v.z), f2b(v.w) };
  *(ushort4*)((half ? We : Wx) + j) = ov;
}

// x = emb[toks] -> bf16 into ginB[:, 0:512] (row stride 1024)
__global__ __launch_bounds__(256) void k_embed(const int* __restrict__ toks, const float* __restrict__ emb,
                                               ushort* __restrict__ ginB) {
  int i = (blockIdx.x * 256 + threadIdx.x) * 4;
  int row = i >> 9, c = i & 511;
  int tok = toks[row];
  float4 v = *(const float4*)(emb + (size_t)tok * HH + c);
  ushort4 ov = { f2b(v.x), f2b(v.y), f2b(v.z), f2b(v.w) };
  *(ushort4*)(ginB + (size_t)row * 1024 + c) = ov;
}

// ---------------- bf16 MFMA GEMM (fp32 out) ----------------
__global__ __launch_bounds__(256) void k_gemm(const ushort* __restrict__ A, int lda,
                                              const ushort* __restrict__ B,
                                              const float* __restrict__ bias,
                                              float* __restrict__ C, int ldc, int K) {
  __shared__ ushort sA[128 * 32];
  __shared__ ushort sB[128 * 32];
  const int tid  = threadIdx.x;
  const int bm   = blockIdx.y * 128;
  const int bn   = blockIdx.x * 128;
  const int lane = tid & 63;
  const int wave = tid >> 6;
  const int wm   = (wave >> 1) * 64;
  const int wn   = (wave & 1) * 64;
  const int m16  = lane & 15;
  const int quad = lane >> 4;

  f32x4 acc[4][4] = {};

  for (int k0 = 0; k0 < K; k0 += 32) {
#pragma unroll
    for (int q = 0; q < 2; ++q) {
      int idx = q * 256 + tid;
      int row = idx >> 2;
      int kc  = (idx & 3) << 3;
      uint4 va = *(const uint4*)(A + (size_t)(bm + row) * lda + k0 + kc);
      *(uint4*)(&sA[idx * 8]) = va;
      uint4 vb = *(const uint4*)(B + (size_t)(bn + row) * K + k0 + kc);
      *(uint4*)(&sB[idx * 8]) = vb;
    }
    __syncthreads();
    short8 a[4], b[4];
#pragma unroll
    for (int i = 0; i < 4; ++i)
      a[i] = *(const short8*)(&sA[(wm + i * 16 + m16) * 32 + quad * 8]);
#pragma unroll
    for (int j = 0; j < 4; ++j)
      b[j] = *(const short8*)(&sB[(wn + j * 16 + m16) * 32 + quad * 8]);
#pragma unroll
    for (int i = 0; i < 4; ++i)
#pragma unroll
      for (int j = 0; j < 4; ++j)
        acc[i][j] = __builtin_amdgcn_mfma_f32_16x16x32_bf16(a[i], b[j], acc[i][j], 0, 0, 0);
    __syncthreads();
  }
#pragma unroll
  for (int i = 0; i < 4; ++i) {
    int gm = bm + wm + i * 16 + quad * 4;
#pragma unroll
    for (int j = 0; j < 4; ++j) {
      int gn = bn + wn + j * 16 + m16;
      float bv = bias ? bias[gn] : 0.f;
#pragma unroll
      for (int r = 0; r < 4; ++r)
        C[(size_t)(gm + r) * ldc + gn] = acc[i][j][r] + bv;
    }
  }
}

// same GEMM but bf16 output (for gi0)
__global__ __launch_bounds__(256) void k_gemm_b16(const ushort* __restrict__ A, int lda,
                                                  const ushort* __restrict__ B,
                                                  const float* __restrict__ bias,
                                                  ushort* __restrict__ C, int ldc, int K) {
  __shared__ ushort sA[128 * 32];
  __shared__ ushort sB[128 * 32];
  const int tid  = threadIdx.x;
  const int bm   = blockIdx.y * 128;
  const int bn   = blockIdx.x * 128;
  const int lane = tid & 63;
  const int wave = tid >> 6;
  const int wm   = (wave >> 1) * 64;
  const int wn   = (wave & 1) * 64;
  const int m16  = lane & 15;
  const int quad = lane >> 4;

  f32x4 acc[4][4] = {};

  for (int k0 = 0; k0 < K; k0 += 32) {
#pragma unroll
    for (int q = 0; q < 2; ++q) {
      int idx = q * 256 + tid;
      int row = idx >> 2;
      int kc  = (idx & 3) << 3;
      uint4 va = *(const uint4*)(A + (size_t)(bm + row) * lda + k0 + kc);
      *(uint4*)(&sA[idx * 8]) = va;
      uint4 vb = *(const uint4*)(B + (size_t)(bn + row) * K + k0 + kc);
      *(uint4*)(&sB[idx * 8]) = vb;
    }
    __syncthreads();
    short8 a[4], b[4];
#pragma unroll
    for (int i = 0; i < 4; ++i)
      a[i] = *(const short8*)(&sA[(wm + i * 16 + m16) * 32 + quad * 8]);
#pragma unroll
    for (int j = 0; j < 4; ++j)
      b[j] = *(const short8*)(&sB[(wn + j * 16 + m16) * 32 + quad * 8]);
#pragma unroll
    for (int i = 0; i < 4; ++i)
#pragma unroll
      for (int j = 0; j < 4; ++j)
        acc[i][j] = __builtin_amdgcn_mfma_f32_16x16x32_bf16(a[i], b[j], acc[i][j], 0, 0, 0);
    __syncthreads();
  }
#pragma unroll
  for (int i = 0; i < 4; ++i) {
    int gm = bm + wm + i * 16 + quad * 4;
#pragma unroll
    for (int j = 0; j < 4; ++j) {
      int gn = bn + wn + j * 16 + m16;
      float bv = bias ? bias[gn] : 0.f;
#pragma unroll
      for (int r = 0; r < 4; ++r)
        C[(size_t)(gm + r) * ldc + gn] = f2b(acc[i][j][r] + bv);
    }
  }
}

// ---------------- attention ----------------
__global__ __launch_bounds__(256) void k_scores(const float* __restrict__ xproj,
                                                const float* __restrict__ encp,
                                                const float* __restrict__ vaW,
                                                float* __restrict__ e) {
  int t2g = blockIdx.x >> 5;
  int b   = blockIdx.x & 31;
  __shared__ float sx[4][512];
  int tid = threadIdx.x;
  for (int i = tid; i < 4 * 512; i += 256) {
    int tt = i >> 9, h = i & 511;
    sx[tt][h] = xproj[((size_t)(t2g * 4 + tt) * BB + b) * HH + h];
  }
  __syncthreads();
  int lane = tid & 63, w = tid >> 6;
  int h8 = lane * 8;
  float va[8];
#pragma unroll
  for (int j = 0; j < 8; ++j) va[j] = vaW[h8 + j];
  for (int t1 = w; t1 < T1N; t1 += 4) {
    const float* ep = encp + ((size_t)t1 * BB + b) * HH + h8;
    float ev[8];
    *(float4*)&ev[0] = *(const float4*)ep;
    *(float4*)&ev[4] = *(const float4*)(ep + 4);
    float s0 = 0, s1 = 0, s2 = 0, s3 = 0;
#pragma unroll
    for (int j = 0; j < 8; ++j) {
      float epj = ev[j], vj = va[j];
      s0 += fast_tanh(sx[0][h8 + j] + epj) * vj;
      s1 += fast_tanh(sx[1][h8 + j] + epj) * vj;
      s2 += fast_tanh(sx[2][h8 + j] + epj) * vj;
      s3 += fast_tanh(sx[3][h8 + j] + epj) * vj;
    }
#pragma unroll
    for (int off = 32; off; off >>= 1) {
      s0 += __shfl_down(s0, off);
      s1 += __shfl_down(s1, off);
      s2 += __shfl_down(s2, off);
      s3 += __shfl_down(s3, off);
    }
    if (lane == 0) {
      size_t base = ((size_t)(t2g * 4) * BB + b) * T1N + t1;
      e[base]                 = s0;
      e[base + 1 * BB * T1N]  = s1;
      e[base + 2 * BB * T1N]  = s2;
      e[base + 3 * BB * T1N]  = s3;
    }
  }
}

__global__ __launch_bounds__(128) void k_softmax(const float* __restrict__ e, float* __restrict__ score,
                                                 float* __restrict__ out_last) {
  int row = blockIdx.x;
  int tid = threadIdx.x;
  float v = e[(size_t)row * T1N + tid];
  __shared__ float red[128];
  red[tid] = v; __syncthreads();
  for (int s = 64; s; s >>= 1) { if (tid < s) red[tid] = fmaxf(red[tid], red[tid + s]); __syncthreads(); }
  float mx = red[0]; __syncthreads();
  float p = __expf(v - mx);
  red[tid] = p; __syncthreads();
  for (int s = 64; s; s >>= 1) { if (tid < s) red[tid] += red[tid + s]; __syncthreads(); }
  float sc = p / red[0];
  score[(size_t)row * T1N + tid] = sc;
  if ((row >> 5) == T2N - 1) out_last[tid * BB + (row & 31)] = sc;
}

__global__ __launch_bounds__(256) void k_attv(const float* __restrict__ enc, const float* __restrict__ score,
                                              ushort* __restrict__ ginB) {
  int t2g = blockIdx.x >> 5;
  int b   = blockIdx.x & 31;
  __shared__ float ssc[8][T1N];
  int tid = threadIdx.x;
  for (int i = tid; i < 8 * T1N; i += 256) {
    int j = i >> 7, t1 = i & 127;
    ssc[j][t1] = score[((size_t)(t2g * 8 + j) * BB + b) * T1N + t1];
  }
  __syncthreads();
  float a0[8] = {}, a1[8] = {};
  for (int t1 = 0; t1 < T1N; ++t1) {
    const float* er = enc + ((size_t)t1 * BB + b) * HH;
    float e0 = er[tid], e1 = er[tid + 256];
#pragma unroll
    for (int j = 0; j < 8; ++j) { a0[j] += e0 * ssc[j][t1]; a1[j] += e1 * ssc[j][t1]; }
  }
#pragma unroll
  for (int j = 0; j < 8; ++j) {
    size_t r = (size_t)(t2g * 8 + j) * BB + b;
    ginB[r * 1024 + 512 + tid]       = f2b(a0[j]);
    ginB[r * 1024 + 512 + tid + 256] = f2b(a1[j]);
  }
}

// ---------------- persistent cooperative recurrence ----------------
// GRU elementwise pair helper
__device__ __forceinline__ void gru_pair(uint gr, uint gz, uint gn, uint hr, uint hz, uint hn,
                                         float hold0, float hold1, float& o0, float& o1) {
  float r0 = fsig(blo(gr) + blo(hr));
  float r1 = fsig(bhi(gr) + bhi(hr));
  float z0 = fsig(blo(gz) + blo(hz));
  float z1 = fsig(bhi(gz) + bhi(hz));
  float n0 = fast_tanh(blo(gn) + r0 * blo(hn));
  float n1 = fast_tanh(bhi(gn) + r1 * bhi(hn));
  o0 = (1.f - z0) * n0 + z0 * hold0;
  o1 = (1.f - z1) * n1 + z1 * hold1;
}

// Grid barrier: sense-reversing, one agent-scope RMW per block.
// bar[0]=arrival count, bar[16]=generation (separate 64B lines).
// Spin uses ACQUIRE loads: each poll performs the gfx950 L2 invalidate, so a
// stale cached generation can never persist (deadlock-proof), and the
// release->acquire chain carries visibility of all pre-barrier stores
// (arriver release-RMW -> flipper acqrel-RMW -> flipper release-store ->
// waker acquire-load).
__device__ __forceinline__ void gbar(unsigned* bar, unsigned nblk) {
  __syncthreads();              // all waves' stores retired (vmcnt drained)
  if (threadIdx.x == 0) {
    unsigned g = __hip_atomic_load(bar + 16, __ATOMIC_RELAXED, __HIP_MEMORY_SCOPE_AGENT);
    unsigned old = __hip_atomic_fetch_add(bar, 1u, __ATOMIC_ACQ_REL, __HIP_MEMORY_SCOPE_AGENT);
    if (old == nblk - 1u) {
      __hip_atomic_store(bar, 0u, __ATOMIC_RELAXED, __HIP_MEMORY_SCOPE_AGENT);
      __hip_atomic_store(bar + 16, g + 1u, __ATOMIC_RELEASE, __HIP_MEMORY_SCOPE_AGENT);
    } else {
      while (__hip_atomic_load(bar + 16, __ATOMIC_ACQUIRE, __HIP_MEMORY_SCOPE_AGENT) == g)
        __builtin_amdgcn_s_sleep(2);
    }
  }
  __syncthreads();
}

__global__ void k_bar_init(unsigned* bar) { bar[0] = 0u; bar[16] = 0u; }

struct RecurP {
  const ushort* Whh0B; const ushort* Whh1B; const ushort* Wih1B;
  const float* bhh0; const float* bhh1; const float* bih1;
  const ushort* gi0B;
  const float* state;     // (2,B,H) fp32
  const ushort* stateB;   // bf16 h0 init
  ushort* gh0x;
  ushort* gh1b0; ushort* gh1b1;
  ushort* gi1x;
  float* h0b0; float* h0b1;
  float* h1b0; float* h1b1;
  ushort* h0B0; ushort* h0B1;
  float* h_out;           // d_out h section (2,B,H)
  ushort* ysB;            // (T2N,B,H) bf16
  unsigned* bar;          // grid barrier state
};

// One cooperative launch; custom acquire-spin barrier replaces cg::grid.sync.
// Weight slices (3 x 32 rows x 512 bf16 = 96 KB) staged in LDS once, so the
// barrier's per-round L2 invalidations never force weight re-fetches.
// LDS total 133120 B (< 160 KB), 1 block/CU.
__global__ __launch_bounds__(256, 1) void k_recur(RecurP p) {
  __shared__ ushort sH[32 * 520];
  __shared__ ushort sW0[32 * 520];
  __shared__ ushort sW1[32 * 520];
  __shared__ ushort sWi[32 * 520];
  const int tid  = threadIdx.x;
  const int blk  = blockIdx.x;
  const int lane = tid & 63, wave = tid >> 6;
  const int bt = wave & 1, nt = wave >> 1;
  const int m16 = lane & 15, quad = lane >> 4;
  const int nrow = blk * 32 + nt * 16 + m16;
  const int k0 = tid * 2;
  const unsigned nblk = gridDim.x;
  const float* state1 = p.state + BB * HH;

  const float bv0 = p.bhh0[nrow];
  const float bv1 = p.bhh1[nrow];
  const float bvi = p.bih1[nrow];
  const int brow = bt * 16 + quad * 4;

  // stage this block's weight slices into LDS (read once from L2/HBM)
  for (int i = tid * 4; i < 32 * 512; i += 256 * 4) {
    int row = i >> 9, col = i & 511;
    size_t g = (size_t)(blk * 32 + row) * 512 + col;
    *(uint2*)(&sW0[row * 520 + col]) = *(const uint2*)(p.Whh0B + g);
    *(uint2*)(&sW1[row * 520 + col]) = *(const uint2*)(p.Whh1B + g);
    *(uint2*)(&sWi[row * 520 + col]) = *(const uint2*)(p.Wih1B + g);
  }

#pragma unroll 1
  for (int t = 0; t < T2N; ++t) {
    const int par = t & 1;
    // ---------------- phase A (was k_stepA) ----------------
    if (t == 0) {
      for (int i = tid; i < 16384; i += 256) {
        int b = i >> 9, k = i & 511;
        sH[b * 520 + k] = f2b(state1[i]);
      }
    } else {
      const ushort* gh1in = par ? p.gh1b0 : p.gh1b1;              // gh1buf[(t+1)&1]
      const float*  h1in  = (t <= 1) ? state1 : (par ? p.h1b1 : p.h1b0); // h1buf[t&1]
      float*        h1out = par ? p.h1b0 : p.h1b1;                // h1buf[(t+1)&1]
      ushort*       ysprev = p.ysB + (size_t)(t - 1) * BB * HH;
#pragma unroll 4
      for (int b = 0; b < 32; ++b) {
        const ushort* gi = p.gi1x + b * 1536 + k0;
        const ushort* gh = gh1in + b * 1536 + k0;
        uint gir = *(const uint*)(gi);
        uint giz = *(const uint*)(gi + 512);
        uint gin = *(const uint*)(gi + 1024);
        uint hr  = *(const uint*)(gh);
        uint hz  = *(const uint*)(gh + 512);
        uint hn  = *(const uint*)(gh + 1024);
        float2 hold = *(const float2*)(h1in + b * 512 + k0);
        float o0, o1;
        gru_pair(gir, giz, gin, hr, hz, hn, hold.x, hold.y, o0, o1);
        uint hb = (uint)f2b(o0) | ((uint)f2b(o1) << 16);
        *(uint*)(&sH[b * 520 + k0]) = hb;
        if (blk == b) {
          *(float2*)(h1out + b * 512 + k0) = make_float2(o0, o1);
          *(uint*)(ysprev + b * 512 + k0) = hb;
        }
      }
    }
    __syncthreads();

    {
      const ushort* h0Bin = (t == 0) ? p.stateB : (par ? p.h0B0 : p.h0B1); // h0bufB[(t+1)&1]
      ushort* gh1out = par ? p.gh1b1 : p.gh1b0;                            // gh1buf[t&1]
      f32x4 acc0 = {0.f, 0.f, 0.f, 0.f}, acc1 = {0.f, 0.f, 0.f, 0.f};
      const ushort* Arow0  = h0Bin + (bt * 16 + m16) * 512 + quad * 8;
      const ushort* Brow0  = &sW0[(nt * 16 + m16) * 520 + quad * 8];
      const ushort* Brow1  = &sW1[(nt * 16 + m16) * 520 + quad * 8];
      const ushort* sArow1 = &sH[(bt * 16 + m16) * 520 + quad * 8];
#pragma unroll 4
      for (int kc = 0; kc < 16; ++kc) {
        short8 a0 = *(const short8*)(Arow0 + kc * 32);
        short8 b0 = *(const short8*)(Brow0 + kc * 32);
        acc0 = __builtin_amdgcn_mfma_f32_16x16x32_bf16(a0, b0, acc0, 0, 0, 0);
        short8 a1 = *(const short8*)(sArow1 + kc * 32);
        short8 b1 = *(const short8*)(Brow1 + kc * 32);
        acc1 = __builtin_amdgcn_mfma_f32_16x16x32_bf16(a1, b1, acc1, 0, 0, 0);
      }
#pragma unroll
      for (int r = 0; r < 4; ++r) {
        p.gh0x[(brow + r) * 1536 + nrow] = f2b(acc0[r] + bv0);
        gh1out[(brow + r) * 1536 + nrow] = f2b(acc1[r] + bv1);
      }
    }
    gbar(p.bar, nblk);

    // ---------------- phase B (was k_stepB) ----------------
    {
      const ushort* gi0t  = p.gi0B + (size_t)t * 32 * 1536;
      const float*  h0in  = (t == 0) ? p.state : (par ? p.h0b0 : p.h0b1); // h0buf[(t+1)&1]
      float*        h0out = par ? p.h0b1 : p.h0b0;                        // h0buf[t&1]
      ushort*       h0Bout = par ? p.h0B1 : p.h0B0;                       // h0bufB[t&1]
#pragma unroll 4
      for (int b = 0; b < 32; ++b) {
        const ushort* gi = gi0t + b * 1536 + k0;
        const ushort* gh = p.gh0x + b * 1536 + k0;
        uint gir = *(const uint*)(gi);
        uint giz = *(const uint*)(gi + 512);
        uint gin = *(const uint*)(gi + 1024);
        uint hr  = *(const uint*)(gh);
        uint hz  = *(const uint*)(gh + 512);
        uint hn  = *(const uint*)(gh + 1024);
        float2 hold = *(const float2*)(h0in + b * 512 + k0);
        float o0, o1;
        gru_pair(gir, giz, gin, hr, hz, hn, hold.x, hold.y, o0, o1);
        uint hb = (uint)f2b(o0) | ((uint)f2b(o1) << 16);
        *(uint*)(&sH[b * 520 + k0]) = hb;
        if (blk == b) {
          *(float2*)(h0out + b * 512 + k0) = make_float2(o0, o1);
          *(uint*)(h0Bout + b * 512 + k0) = hb;
        }
      }
      __syncthreads();

      f32x4 acc = {0.f, 0.f, 0.f, 0.f};
      const ushort* Brow  = &sWi[(nt * 16 + m16) * 520 + quad * 8];
      const ushort* sArow = &sH[(bt * 16 + m16) * 520 + quad * 8];
#pragma unroll 4
      for (int kc = 0; kc < 16; ++kc) {
        short8 a = *(const short8*)(sArow + kc * 32);
        short8 b = *(const short8*)(Brow + kc * 32);
        acc = __builtin_amdgcn_mfma_f32_16x16x32_bf16(a, b, acc, 0, 0, 0);
      }
#pragma unroll
      for (int r = 0; r < 4; ++r)
        p.gi1x[(brow + r) * 1536 + nrow] = f2b(acc[r] + bvi);
    }
    gbar(p.bar, nblk);
  }

  // ---------------- final (was k_final): h1(63), ys[63], out_h ----------------
  if (blk < 32) {
    const int b = blk;
    const ushort* gi = p.gi1x + b * 1536 + k0;
    const ushort* gh = p.gh1b1 + b * 1536 + k0;   // gh1buf[63&1] = gh1buf[1]
    uint gir = *(const uint*)(gi);
    uint giz = *(const uint*)(gi + 512);
    uint gin = *(const uint*)(gi + 1024);
    uint hr  = *(const uint*)(gh);
    uint hz  = *(const uint*)(gh + 512);
    uint hn  = *(const uint*)(gh + 1024);
    float2 hold = *(const float2*)(p.h1b0 + b * 512 + k0);  // h1buf[(63+1)&1] = h1(62)
    float o0, o1;
    gru_pair(gir, giz, gin, hr, hz, hn, hold.x, hold.y, o0, o1);
    *(uint*)(p.ysB + (size_t)63 * BB * HH + b * 512 + k0) = (uint)f2b(o0) | ((uint)f2b(o1) << 16);
    p.h_out[16384 + b * 512 + k0]     = o0;
    p.h_out[16384 + b * 512 + k0 + 1] = o1;
    float2 h0p = *(const float2*)(p.h0b1 + b * 512 + k0);   // h0buf[63&1] = h0(63)
    *(float2*)(p.h_out + b * 512 + k0) = h0p;
  }
}

// ---------------- launch ----------------
extern "C" void kernel_launch(void* const* d_in, const int* in_sizes, int n_in,
                              void* d_out, int out_size, void* d_ws, size_t ws_size,
                              hipStream_t stream) {
  const int*   toks  = (const int*)d_in[0];
  const float* state = (const float*)d_in[1];
  const float* enc   = (const float*)d_in[2];
  const float* emb   = (const float*)d_in[3];
  const float* wa_W  = (const float*)d_in[4];
  const float* wa_b  = (const float*)d_in[5];
  const float* va    = (const float*)d_in[6];
  const float* b_ih0 = (const float*)d_in[9];
  const float* b_hh0 = (const float*)d_in[10];
  const float* b_ih1 = (const float*)d_in[13];
  const float* b_hh1 = (const float*)d_in[14];
  const float* out_W = (const float*)d_in[15];
  const float* out_b = (const float*)d_in[16];
  const float* W_ih0 = (const float*)d_in[7];
  const float* W_hh0 = (const float*)d_in[8];
  const float* W_ih1 = (const float*)d_in[11];
  const float* W_hh1 = (const float*)d_in[12];

  float* y_out  = (float*)d_out;
  float* h_out  = y_out + (size_t)T2N * BB * VV;
  float* ls_out = h_out + 2 * BB * HH;

  char* ws = (char*)d_ws;
  size_t off = 0;
  auto alloc = [&](size_t bytes) -> void* {
    void* p = ws + off;
    off += (bytes + 255) & ~(size_t)255;
    return p;
  };
  ushort* encB   = (ushort*)alloc((size_t)T1N * BB * HH * 2);
  ushort* ginB   = (ushort*)alloc((size_t)T2N * BB * 2 * HH * 2);
  ushort* WeB    = (ushort*)alloc((size_t)HH * HH * 2);
  ushort* WxB    = (ushort*)alloc((size_t)HH * HH * 2);
  ushort* Wih0B  = (ushort*)alloc((size_t)3 * HH * 2 * HH * 2);
  ushort* Whh0B  = (ushort*)alloc((size_t)3 * HH * HH * 2);
  ushort* Wih1B  = (ushort*)alloc((size_t)3 * HH * HH * 2);
  ushort* Whh1B  = (ushort*)alloc((size_t)3 * HH * HH * 2);
  ushort* outWB  = (ushort*)alloc((size_t)VV * HH * 2);
  ushort* stateB = (ushort*)alloc((size_t)BB * HH * 2);
  float* encproj = (float*)alloc((size_t)T1N * BB * HH * 4);
  float* xproj   = (float*)alloc((size_t)T2N * BB * HH * 4);
  float* eM      = (float*)alloc((size_t)T2N * BB * T1N * 4);
  float* score   = (float*)alloc((size_t)T2N * BB * T1N * 4);
  ushort* gi0B   = (ushort*)alloc((size_t)T2N * BB * 3 * HH * 2);
  ushort* gh0x   = (ushort*)alloc((size_t)BB * 3 * HH * 2);
  ushort* gh1buf0 = (ushort*)alloc((size_t)BB * 3 * HH * 2);
  ushort* gh1buf1 = (ushort*)alloc((size_t)BB * 3 * HH * 2);
  ushort* gi1x   = (ushort*)alloc((size_t)BB * 3 * HH * 2);
  float* h0buf0  = (float*)alloc((size_t)BB * HH * 4);
  float* h0buf1  = (float*)alloc((size_t)BB * HH * 4);
  float* h1buf0  = (float*)alloc((size_t)BB * HH * 4);
  float* h1buf1  = (float*)alloc((size_t)BB * HH * 4);
  ushort* h0bufB0 = (ushort*)alloc((size_t)BB * HH * 2);
  ushort* h0bufB1 = (ushort*)alloc((size_t)BB * HH * 2);
  ushort* ysB    = (ushort*)alloc((size_t)T2N * BB * HH * 2);
  unsigned* bar  = (unsigned*)alloc(256);

  // preamble
  k_bar_init<<<1, 1, 0, stream>>>(bar);
  k_cvt<<<VV * HH / 1024, 256, 0, stream>>>(out_W, outWB, VV * HH);
  k_cvt<<<T1N * BB * HH / 1024, 256, 0, stream>>>(enc, encB, T1N * BB * HH);
  k_cvt<<<3 * HH * 2 * HH / 1024, 256, 0, stream>>>(W_ih0, Wih0B, 3 * HH * 2 * HH);
  k_cvt<<<3 * HH * HH / 1024, 256, 0, stream>>>(W_hh0, Whh0B, 3 * HH * HH);
  k_cvt<<<3 * HH * HH / 1024, 256, 0, stream>>>(W_ih1, Wih1B, 3 * HH * HH);
  k_cvt<<<3 * HH * HH / 1024, 256, 0, stream>>>(W_hh1, Whh1B, 3 * HH * HH);
  k_cvt<<<BB * HH / 1024, 256, 0, stream>>>(state, stateB, BB * HH);
  k_cvt_wa<<<2 * HH * HH / 1024, 256, 0, stream>>>(wa_W, WxB, WeB);
  k_embed<<<T2N * BB * HH / 1024, 256, 0, stream>>>(toks, emb, ginB);

  k_gemm<<<dim3(HH / 128, T1N * BB / 128), 256, 0, stream>>>(encB, HH, WeB, wa_b, encproj, HH, HH);
  k_gemm<<<dim3(HH / 128, T2N * BB / 128), 256, 0, stream>>>(ginB, 2 * HH, WxB, nullptr, xproj, HH, HH);

  k_scores<<<512, 256, 0, stream>>>(xproj, encproj, va, eM);
  k_softmax<<<T2N * BB, 128, 0, stream>>>(eM, score, ls_out);
  k_attv<<<256, 256, 0, stream>>>(enc, score, ginB);

  k_gemm_b16<<<dim3(3 * HH / 128, T2N * BB / 128), 256, 0, stream>>>(ginB, 2 * HH, Wih0B, b_ih0, gi0B, 3 * HH, 2 * HH);

  // recurrence: single persistent cooperative kernel, custom grid barrier
  RecurP rp;
  rp.Whh0B = Whh0B; rp.Whh1B = Whh1B; rp.Wih1B = Wih1B;
  rp.bhh0 = b_hh0; rp.bhh1 = b_hh1; rp.bih1 = b_ih1;
  rp.gi0B = gi0B;
  rp.state = state; rp.stateB = stateB;
  rp.gh0x = gh0x;
  rp.gh1b0 = gh1buf0; rp.gh1b1 = gh1buf1;
  rp.gi1x = gi1x;
  rp.h0b0 = h0buf0; rp.h0b1 = h0buf1;
  rp.h1b0 = h1buf0; rp.h1b1 = h1buf1;
  rp.h0B0 = h0bufB0; rp.h0B1 = h0bufB1;
  rp.h_out = h_out; rp.ysB = ysB;
  rp.bar = bar;
  void* kargs[] = { &rp };
  hipLaunchCooperativeKernel((const void*)k_recur, dim3(48), dim3(256), kargs, 0, stream);

  // y = ys @ out_W^T + out_b
  k_gemm<<<dim3(VV / 128, T2N * BB / 128), 256, 0, stream>>>(ysB, HH, outWB, out_b, y_out, VV, HH);
}

// Round 4
// 3631.472 us; speedup vs baseline: 1.2392x; 1.0460x over previous
//
#include <hip/hip_runtime.h>
#include <hip/hip_bf16.h>
#include <stdint.h>

#define HH   512
#define VV   32000
#define T1N  128
#define T2N  64
#define BB   32

typedef __attribute__((ext_vector_type(8))) short short8;
typedef __attribute__((ext_vector_type(4))) float f32x4;

__device__ __forceinline__ ushort f2b(float f) {
  unsigned u = __float_as_uint(f);
  unsigned r = (u + 0x7fffu + ((u >> 16) & 1u)) >> 16;
  return (ushort)r;
}
__device__ __forceinline__ float blo(unsigned u){ return __uint_as_float(u << 16); }
__device__ __forceinline__ float bhi(unsigned u){ return __uint_as_float(u & 0xffff0000u); }

__device__ __forceinline__ float fast_tanh(float x) {
  float ax = fabsf(x);
  float e  = __expf(-2.f * ax);
  float t  = (1.f - e) / (1.f + e);
  return x < 0.f ? -t : t;
}
__device__ __forceinline__ float fsig(float x) { return 1.f / (1.f + __expf(-x)); }

// ---------------- conversions ----------------
__global__ __launch_bounds__(256) void k_cvt(const float* __restrict__ s, ushort* __restrict__ d, int n) {
  int i = (blockIdx.x * 256 + threadIdx.x) * 4;
  if (i < n) {
    float4 v = *(const float4*)(s + i);
    ushort4 o = { f2b(v.x), f2b(v.y), f2b(v.z), f2b(v.w) };
    *(ushort4*)(d + i) = o;
  }
}

// wa_W (512,1024) -> WxB = wa_W[:, :512], WeB = wa_W[:, 512:]
__global__ __launch_bounds__(256) void k_cvt_wa(const float* __restrict__ wa,
                                                ushort* __restrict__ Wx, ushort* __restrict__ We) {
  int i = (blockIdx.x * 256 + threadIdx.x) * 4;
  int half = (i >= HH * HH);
  int j = i & (HH * HH - 1);
  int o = j >> 9, c = j & 511;
  const float* s = wa + (size_t)o * 1024 + c + (half ? 512 : 0);
  float4 v = *(const float4*)s;
  ushort4 ov = { f2b(v.x), f2b(v.y), f2b(v.z), f2b(v.w) };
  *(ushort4*)((half ? We : Wx) + j) = ov;
}

// x = emb[toks] -> bf16 into ginB[:, 0:512] (row stride 1024)
__global__ __launch_bounds__(256) void k_embed(const int* __restrict__ toks, const float* __restrict__ emb,
                                               ushort* __restrict__ ginB) {
  int i = (blockIdx.x * 256 + threadIdx.x) * 4;
  int row = i >> 9, c = i & 511;
  int tok = toks[row];
  float4 v = *(const float4*)(emb + (size_t)tok * HH + c);
  ushort4 ov = { f2b(v.x), f2b(v.y), f2b(v.z), f2b(v.w) };
  *(ushort4*)(ginB + (size_t)row * 1024 + c) = ov;
}

// ---------------- bf16 MFMA GEMM (fp32 out) ----------------
__global__ __launch_bounds__(256) void k_gemm(const ushort* __restrict__ A, int lda,
                                              const ushort* __restrict__ B,
                                              const float* __restrict__ bias,
                                              float* __restrict__ C, int ldc, int K) {
  __shared__ ushort sA[128 * 32];
  __shared__ ushort sB[128 * 32];
  const int tid  = threadIdx.x;
  const int bm   = blockIdx.y * 128;
  const int bn   = blockIdx.x * 128;
  const int lane = tid & 63;
  const int wave = tid >> 6;
  const int wm   = (wave >> 1) * 64;
  const int wn   = (wave & 1) * 64;
  const int m16  = lane & 15;
  const int quad = lane >> 4;

  f32x4 acc[4][4] = {};

  for (int k0 = 0; k0 < K; k0 += 32) {
#pragma unroll
    for (int q = 0; q < 2; ++q) {
      int idx = q * 256 + tid;
      int row = idx >> 2;
      int kc  = (idx & 3) << 3;
      uint4 va = *(const uint4*)(A + (size_t)(bm + row) * lda + k0 + kc);
      *(uint4*)(&sA[idx * 8]) = va;
      uint4 vb = *(const uint4*)(B + (size_t)(bn + row) * K + k0 + kc);
      *(uint4*)(&sB[idx * 8]) = vb;
    }
    __syncthreads();
    short8 a[4], b[4];
#pragma unroll
    for (int i = 0; i < 4; ++i)
      a[i] = *(const short8*)(&sA[(wm + i * 16 + m16) * 32 + quad * 8]);
#pragma unroll
    for (int j = 0; j < 4; ++j)
      b[j] = *(const short8*)(&sB[(wn + j * 16 + m16) * 32 + quad * 8]);
#pragma unroll
    for (int i = 0; i < 4; ++i)
#pragma unroll
      for (int j = 0; j < 4; ++j)
        acc[i][j] = __builtin_amdgcn_mfma_f32_16x16x32_bf16(a[i], b[j], acc[i][j], 0, 0, 0);
    __syncthreads();
  }
#pragma unroll
  for (int i = 0; i < 4; ++i) {
    int gm = bm + wm + i * 16 + quad * 4;
#pragma unroll
    for (int j = 0; j < 4; ++j) {
      int gn = bn + wn + j * 16 + m16;
      float bv = bias ? bias[gn] : 0.f;
#pragma unroll
      for (int r = 0; r < 4; ++r)
        C[(size_t)(gm + r) * ldc + gn] = acc[i][j][r] + bv;
    }
  }
}

// same GEMM but bf16 output (for gi0)
__global__ __launch_bounds__(256) void k_gemm_b16(const ushort* __restrict__ A, int lda,
                                                  const ushort* __restrict__ B,
                                                  const float* __restrict__ bias,
                                                  ushort* __restrict__ C, int ldc, int K) {
  __shared__ ushort sA[128 * 32];
  __shared__ ushort sB[128 * 32];
  const int tid  = threadIdx.x;
  const int bm   = blockIdx.y * 128;
  const int bn   = blockIdx.x * 128;
  const int lane = tid & 63;
  const int wave = tid >> 6;
  const int wm   = (wave >> 1) * 64;
  const int wn   = (wave & 1) * 64;
  const int m16  = lane & 15;
  const int quad = lane >> 4;

  f32x4 acc[4][4] = {};

  for (int k0 = 0; k0 < K; k0 += 32) {
#pragma unroll
    for (int q = 0; q < 2; ++q) {
      int idx = q * 256 + tid;
      int row = idx >> 2;
      int kc  = (idx & 3) << 3;
      uint4 va = *(const uint4*)(A + (size_t)(bm + row) * lda + k0 + kc);
      *(uint4*)(&sA[idx * 8]) = va;
      uint4 vb = *(const uint4*)(B + (size_t)(bn + row) * K + k0 + kc);
      *(uint4*)(&sB[idx * 8]) = vb;
    }
    __syncthreads();
    short8 a[4], b[4];
#pragma unroll
    for (int i = 0; i < 4; ++i)
      a[i] = *(const short8*)(&sA[(wm + i * 16 + m16) * 32 + quad * 8]);
#pragma unroll
    for (int j = 0; j < 4; ++j)
      b[j] = *(const short8*)(&sB[(wn + j * 16 + m16) * 32 + quad * 8]);
#pragma unroll
    for (int i = 0; i < 4; ++i)
#pragma unroll
      for (int j = 0; j < 4; ++j)
        acc[i][j] = __builtin_amdgcn_mfma_f32_16x16x32_bf16(a[i], b[j], acc[i][j], 0, 0, 0);
    __syncthreads();
  }
#pragma unroll
  for (int i = 0; i < 4; ++i) {
    int gm = bm + wm + i * 16 + quad * 4;
#pragma unroll
    for (int j = 0; j < 4; ++j) {
      int gn = bn + wn + j * 16 + m16;
      float bv = bias ? bias[gn] : 0.f;
#pragma unroll
      for (int r = 0; r < 4; ++r)
        C[(size_t)(gm + r) * ldc + gn] = f2b(acc[i][j][r] + bv);
    }
  }
}

// ---------------- attention ----------------
__global__ __launch_bounds__(256) void k_scores(const float* __restrict__ xproj,
                                                const float* __restrict__ encp,
                                                const float* __restrict__ vaW,
                                                float* __restrict__ e) {
  int t2g = blockIdx.x >> 5;
  int b   = blockIdx.x & 31;
  __shared__ float sx[4][512];
  int tid = threadIdx.x;
  for (int i = tid; i < 4 * 512; i += 256) {
    int tt = i >> 9, h = i & 511;
    sx[tt][h] = xproj[((size_t)(t2g * 4 + tt) * BB + b) * HH + h];
  }
  __syncthreads();
  int lane = tid & 63, w = tid >> 6;
  int h8 = lane * 8;
  float va[8];
#pragma unroll
  for (int j = 0; j < 8; ++j) va[j] = vaW[h8 + j];
  for (int t1 = w; t1 < T1N; t1 += 4) {
    const float* ep = encp + ((size_t)t1 * BB + b) * HH + h8;
    float ev[8];
    *(float4*)&ev[0] = *(const float4*)ep;
    *(float4*)&ev[4] = *(const float4*)(ep + 4);
    float s0 = 0, s1 = 0, s2 = 0, s3 = 0;
#pragma unroll
    for (int j = 0; j < 8; ++j) {
      float epj = ev[j], vj = va[j];
      s0 += fast_tanh(sx[0][h8 + j] + epj) * vj;
      s1 += fast_tanh(sx[1][h8 + j] + epj) * vj;
      s2 += fast_tanh(sx[2][h8 + j] + epj) * vj;
      s3 += fast_tanh(sx[3][h8 + j] + epj) * vj;
    }
#pragma unroll
    for (int off = 32; off; off >>= 1) {
      s0 += __shfl_down(s0, off);
      s1 += __shfl_down(s1, off);
      s2 += __shfl_down(s2, off);
      s3 += __shfl_down(s3, off);
    }
    if (lane == 0) {
      size_t base = ((size_t)(t2g * 4) * BB + b) * T1N + t1;
      e[base]                 = s0;
      e[base + 1 * BB * T1N]  = s1;
      e[base + 2 * BB * T1N]  = s2;
      e[base + 3 * BB * T1N]  = s3;
    }
  }
}

__global__ __launch_bounds__(128) void k_softmax(const float* __restrict__ e, float* __restrict__ score,
                                                 float* __restrict__ out_last) {
  int row = blockIdx.x;
  int tid = threadIdx.x;
  float v = e[(size_t)row * T1N + tid];
  __shared__ float red[128];
  red[tid] = v; __syncthreads();
  for (int s = 64; s; s >>= 1) { if (tid < s) red[tid] = fmaxf(red[tid], red[tid + s]); __syncthreads(); }
  float mx = red[0]; __syncthreads();
  float p = __expf(v - mx);
  red[tid] = p; __syncthreads();
  for (int s = 64; s; s >>= 1) { if (tid < s) red[tid] += red[tid + s]; __syncthreads(); }
  float sc = p / red[0];
  score[(size_t)row * T1N + tid] = sc;
  if ((row >> 5) == T2N - 1) out_last[tid * BB + (row & 31)] = sc;
}

__global__ __launch_bounds__(256) void k_attv(const float* __restrict__ enc, const float* __restrict__ score,
                                              ushort* __restrict__ ginB) {
  int t2g = blockIdx.x >> 5;
  int b   = blockIdx.x & 31;
  __shared__ float ssc[8][T1N];
  int tid = threadIdx.x;
  for (int i = tid; i < 8 * T1N; i += 256) {
    int j = i >> 7, t1 = i & 127;
    ssc[j][t1] = score[((size_t)(t2g * 8 + j) * BB + b) * T1N + t1];
  }
  __syncthreads();
  float a0[8] = {}, a1[8] = {};
  for (int t1 = 0; t1 < T1N; ++t1) {
    const float* er = enc + ((size_t)t1 * BB + b) * HH;
    float e0 = er[tid], e1 = er[tid + 256];
#pragma unroll
    for (int j = 0; j < 8; ++j) { a0[j] += e0 * ssc[j][t1]; a1[j] += e1 * ssc[j][t1]; }
  }
#pragma unroll
  for (int j = 0; j < 8; ++j) {
    size_t r = (size_t)(t2g * 8 + j) * BB + b;
    ginB[r * 1024 + 512 + tid]       = f2b(a0[j]);
    ginB[r * 1024 + 512 + tid + 256] = f2b(a1[j]);
  }
}

// ---------------- persistent cooperative recurrence ----------------
// GRU elementwise pair helper
__device__ __forceinline__ void gru_pair(uint gr, uint gz, uint gn, uint hr, uint hz, uint hn,
                                         float hold0, float hold1, float& o0, float& o1) {
  float r0 = fsig(blo(gr) + blo(hr));
  float r1 = fsig(bhi(gr) + bhi(hr));
  float z0 = fsig(blo(gz) + blo(hz));
  float z1 = fsig(bhi(gz) + bhi(hz));
  float n0 = fast_tanh(blo(gn) + r0 * blo(hn));
  float n1 = fast_tanh(bhi(gn) + r1 * bhi(hn));
  o0 = (1.f - z0) * n0 + z0 * hold0;
  o1 = (1.f - z1) * n1 + z1 * hold1;
}

// All barrier counters are accessed exclusively via agent-scope RMWs, which
// execute at the coherence point (fabric/MALL) -- unambiguous cross-XCD
// visibility, no dependence on load cache behavior. Monotone epochs, no resets.
__device__ __forceinline__ unsigned armw(unsigned* p, unsigned v) {
  return __hip_atomic_fetch_add(p, v, __ATOMIC_RELAXED, __HIP_MEMORY_SCOPE_AGENT);
}

#define SPIN_GE(addr, target)                                             \
  {                                                                       \
    unsigned long long _t0 = __builtin_amdgcn_s_memrealtime();            \
    while (armw((addr), 0u) < (target)) {                                 \
      __builtin_amdgcn_s_sleep(1);                                        \
      if (__builtin_amdgcn_s_memrealtime() - _t0 > 5000000ull) break;     \
    }                                                                     \
  }

// Hierarchical XCD-aware grid barrier.
// Layout in bs (uint idx, 64B-spaced): cnt[x]=x*16, census=128, garr=144,
// gwb=160, lgen[x]=176+x*16.
// Per round: every block 1 fabric RMW arrive; per XCD exactly ONE
// wbl2 (leader release) + ONE invl2 (leader acquire); members L1-inv only.
__device__ __forceinline__ void gbarH(unsigned* bs, int myxcd, bool leader,
                                      unsigned nblk, unsigned nxcd, unsigned ep) {
  __syncthreads();          // all waves' stores drained to L2
  if (threadIdx.x == 0) {
    armw(bs + 144, 1u);     // global arrive
    if (leader) {
      SPIN_GE(bs + 144, nblk * ep);                        // all blocks arrived
      __builtin_amdgcn_fence(__ATOMIC_RELEASE, "agent");   // buffer_wbl2: flush this XCD's L2
      armw(bs + 160, 1u);                                  // this XCD flushed
      SPIN_GE(bs + 160, nxcd * ep);                        // all XCDs flushed
      __builtin_amdgcn_fence(__ATOMIC_ACQUIRE, "agent");   // inv this XCD's L1+L2
      armw(bs + 176 + myxcd * 16, 1u);                     // publish local generation
    } else {
      SPIN_GE(bs + 176 + myxcd * 16, ep);                  // own-XCD L2 refreshed
      asm volatile("s_waitcnt vmcnt(0)\n\tbuffer_inv sc0" ::: "memory"); // L1-only inv
    }
  }
  __syncthreads();
}

__global__ void k_bar_init(unsigned* bs) {
  for (int i = threadIdx.x; i < 512; i += 256) bs[i] = 0u;
}

struct RecurP {
  const ushort* Whh0B; const ushort* Whh1B; const ushort* Wih1B;
  const float* bhh0; const float* bhh1; const float* bih1;
  const ushort* gi0B;
  const float* state;     // (2,B,H) fp32
  const ushort* stateB;   // bf16 h0 init
  ushort* gh0x;
  ushort* gh1b0; ushort* gh1b1;
  ushort* gi1x;
  float* h0b0; float* h0b1;
  float* h1b0; float* h1b1;
  ushort* h0B0; ushort* h0B1;
  float* h_out;           // d_out h section (2,B,H)
  ushort* ysB;            // (T2N,B,H) bf16
  unsigned* bar;          // barrier state (512 uints, zeroed)
};

// One cooperative launch; hierarchical XCD barrier. Weight slices in LDS.
__global__ __launch_bounds__(256, 1) void k_recur(RecurP p) {
  __shared__ ushort sH[32 * 520];
  __shared__ ushort sW0[32 * 520];
  __shared__ ushort sW1[32 * 520];
  __shared__ ushort sWi[32 * 520];
  const int tid  = threadIdx.x;
  const int blk  = blockIdx.x;
  const int lane = tid & 63, wave = tid >> 6;
  const int bt = wave & 1, nt = wave >> 1;
  const int m16 = lane & 15, quad = lane >> 4;
  const int nrow = blk * 32 + nt * 16 + m16;
  const int k0 = tid * 2;
  const unsigned nblk = gridDim.x;
  const float* state1 = p.state + BB * HH;
  unsigned* bs = p.bar;

  // ---- XCD census: read XCC_ID, register, elect per-XCD leader ----
  unsigned xcc;
  asm volatile("s_getreg_b32 %0, hwreg(HW_REG_XCC_ID)" : "=s"(xcc));
  xcc &= 7u;
  __shared__ int s_xcd, s_leader, s_nxcd;
  if (tid == 0) {
    unsigned rank = armw(bs + xcc * 16, 1u);
    armw(bs + 128, 1u);                 // census arrive
    SPIN_GE(bs + 128, nblk);            // all registered
    unsigned nx = 0;
    for (int i = 0; i < 8; ++i) nx += (armw(bs + i * 16, 0u) > 0u) ? 1u : 0u;
    s_xcd = (int)xcc; s_leader = (rank == 0u) ? 1 : 0; s_nxcd = (int)nx;
  }
  __syncthreads();
  const int myxcd = s_xcd;
  const bool leader = (s_leader != 0);
  const unsigned nxcd = (unsigned)s_nxcd;

  const float bv0 = p.bhh0[nrow];
  const float bv1 = p.bhh1[nrow];
  const float bvi = p.bih1[nrow];
  const int brow = bt * 16 + quad * 4;

  // stage this block's weight slices into LDS (read once from L2/HBM)
  for (int i = tid * 4; i < 32 * 512; i += 256 * 4) {
    int row = i >> 9, col = i & 511;
    size_t g = (size_t)(blk * 32 + row) * 512 + col;
    *(uint2*)(&sW0[row * 520 + col]) = *(const uint2*)(p.Whh0B + g);
    *(uint2*)(&sW1[row * 520 + col]) = *(const uint2*)(p.Whh1B + g);
    *(uint2*)(&sWi[row * 520 + col]) = *(const uint2*)(p.Wih1B + g);
  }

#pragma unroll 1
  for (int t = 0; t < T2N; ++t) {
    const int par = t & 1;
    // ---------------- phase A (was k_stepA) ----------------
    if (t == 0) {
      for (int i = tid; i < 16384; i += 256) {
        int b = i >> 9, k = i & 511;
        sH[b * 520 + k] = f2b(state1[i]);
      }
    } else {
      const ushort* gh1in = par ? p.gh1b0 : p.gh1b1;              // gh1buf[(t+1)&1]
      const float*  h1in  = (t <= 1) ? state1 : (par ? p.h1b1 : p.h1b0); // h1buf[t&1]
      float*        h1out = par ? p.h1b0 : p.h1b1;                // h1buf[(t+1)&1]
      ushort*       ysprev = p.ysB + (size_t)(t - 1) * BB * HH;
#pragma unroll 4
      for (int b = 0; b < 32; ++b) {
        const ushort* gi = p.gi1x + b * 1536 + k0;
        const ushort* gh = gh1in + b * 1536 + k0;
        uint gir = *(const uint*)(gi);
        uint giz = *(const uint*)(gi + 512);
        uint gin = *(const uint*)(gi + 1024);
        uint hr  = *(const uint*)(gh);
        uint hz  = *(const uint*)(gh + 512);
        uint hn  = *(const uint*)(gh + 1024);
        float2 hold = *(const float2*)(h1in + b * 512 + k0);
        float o0, o1;
        gru_pair(gir, giz, gin, hr, hz, hn, hold.x, hold.y, o0, o1);
        uint hb = (uint)f2b(o0) | ((uint)f2b(o1) << 16);
        *(uint*)(&sH[b * 520 + k0]) = hb;
        if (blk == b) {
          *(float2*)(h1out + b * 512 + k0) = make_float2(o0, o1);
          *(uint*)(ysprev + b * 512 + k0) = hb;
        }
      }
    }
    __syncthreads();

    {
      const ushort* h0Bin = (t == 0) ? p.stateB : (par ? p.h0B0 : p.h0B1); // h0bufB[(t+1)&1]
      ushort* gh1out = par ? p.gh1b1 : p.gh1b0;                            // gh1buf[t&1]
      f32x4 acc0 = {0.f, 0.f, 0.f, 0.f}, acc1 = {0.f, 0.f, 0.f, 0.f};
      const ushort* Arow0  = h0Bin + (bt * 16 + m16) * 512 + quad * 8;
      const ushort* Brow0  = &sW0[(nt * 16 + m16) * 520 + quad * 8];
      const ushort* Brow1  = &sW1[(nt * 16 + m16) * 520 + quad * 8];
      const ushort* sArow1 = &sH[(bt * 16 + m16) * 520 + quad * 8];
#pragma unroll 4
      for (int kc = 0; kc < 16; ++kc) {
        short8 a0 = *(const short8*)(Arow0 + kc * 32);
        short8 b0 = *(const short8*)(Brow0 + kc * 32);
        acc0 = __builtin_amdgcn_mfma_f32_16x16x32_bf16(a0, b0, acc0, 0, 0, 0);
        short8 a1 = *(const short8*)(sArow1 + kc * 32);
        short8 b1 = *(const short8*)(Brow1 + kc * 32);
        acc1 = __builtin_amdgcn_mfma_f32_16x16x32_bf16(a1, b1, acc1, 0, 0, 0);
      }
#pragma unroll
      for (int r = 0; r < 4; ++r) {
        p.gh0x[(brow + r) * 1536 + nrow] = f2b(acc0[r] + bv0);
        gh1out[(brow + r) * 1536 + nrow] = f2b(acc1[r] + bv1);
      }
    }
    gbarH(bs, myxcd, leader, nblk, nxcd, (unsigned)(2 * t + 1));

    // ---------------- phase B (was k_stepB) ----------------
    {
      const ushort* gi0t  = p.gi0B + (size_t)t * 32 * 1536;
      const float*  h0in  = (t == 0) ? p.state : (par ? p.h0b0 : p.h0b1); // h0buf[(t+1)&1]
      float*        h0out = par ? p.h0b1 : p.h0b0;                        // h0buf[t&1]
      ushort*       h0Bout = par ? p.h0B1 : p.h0B0;                       // h0bufB[t&1]
#pragma unroll 4
      for (int b = 0; b < 32; ++b) {
        const ushort* gi = gi0t + b * 1536 + k0;
        const ushort* gh = p.gh0x + b * 1536 + k0;
        uint gir = *(const uint*)(gi);
        uint giz = *(const uint*)(gi + 512);
        uint gin = *(const uint*)(gi + 1024);
        uint hr  = *(const uint*)(gh);
        uint hz  = *(const uint*)(gh + 512);
        uint hn  = *(const uint*)(gh + 1024);
        float2 hold = *(const float2*)(h0in + b * 512 + k0);
        float o0, o1;
        gru_pair(gir, giz, gin, hr, hz, hn, hold.x, hold.y, o0, o1);
        uint hb = (uint)f2b(o0) | ((uint)f2b(o1) << 16);
        *(uint*)(&sH[b * 520 + k0]) = hb;
        if (blk == b) {
          *(float2*)(h0out + b * 512 + k0) = make_float2(o0, o1);
          *(uint*)(h0Bout + b * 512 + k0) = hb;
        }
      }
      __syncthreads();

      f32x4 acc = {0.f, 0.f, 0.f, 0.f};
      const ushort* Brow  = &sWi[(nt * 16 + m16) * 520 + quad * 8];
      const ushort* sArow = &sH[(bt * 16 + m16) * 520 + quad * 8];
#pragma unroll 4
      for (int kc = 0; kc < 16; ++kc) {
        short8 a = *(const short8*)(sArow + kc * 32);
        short8 b = *(const short8*)(Brow + kc * 32);
        acc = __builtin_amdgcn_mfma_f32_16x16x32_bf16(a, b, acc, 0, 0, 0);
      }
#pragma unroll
      for (int r = 0; r < 4; ++r)
        p.gi1x[(brow + r) * 1536 + nrow] = f2b(acc[r] + bvi);
    }
    gbarH(bs, myxcd, leader, nblk, nxcd, (unsigned)(2 * t + 2));
  }

  // ---------------- final (was k_final): h1(63), ys[63], out_h ----------------
  if (blk < 32) {
    const int b = blk;
    const ushort* gi = p.gi1x + b * 1536 + k0;
    const ushort* gh = p.gh1b1 + b * 1536 + k0;   // gh1buf[63&1] = gh1buf[1]
    uint gir = *(const uint*)(gi);
    uint giz = *(const uint*)(gi + 512);
    uint gin = *(const uint*)(gi + 1024);
    uint hr  = *(const uint*)(gh);
    uint hz  = *(const uint*)(gh + 512);
    uint hn  = *(const uint*)(gh + 1024);
    float2 hold = *(const float2*)(p.h1b0 + b * 512 + k0);  // h1buf[(63+1)&1] = h1(62)
    float o0, o1;
    gru_pair(gir, giz, gin, hr, hz, hn, hold.x, hold.y, o0, o1);
    *(uint*)(p.ysB + (size_t)63 * BB * HH + b * 512 + k0) = (uint)f2b(o0) | ((uint)f2b(o1) << 16);
    p.h_out[16384 + b * 512 + k0]     = o0;
    p.h_out[16384 + b * 512 + k0 + 1] = o1;
    float2 h0p = *(const float2*)(p.h0b1 + b * 512 + k0);   // h0buf[63&1] = h0(63)
    *(float2*)(p.h_out + b * 512 + k0) = h0p;
  }
}

// ---------------- launch ----------------
extern "C" void kernel_launch(void* const* d_in, const int* in_sizes, int n_in,
                              void* d_out, int out_size, void* d_ws, size_t ws_size,
                              hipStream_t stream) {
  const int*   toks  = (const int*)d_in[0];
  const float* state = (const float*)d_in[1];
  const float* enc   = (const float*)d_in[2];
  const float* emb   = (const float*)d_in[3];
  const float* wa_W  = (const float*)d_in[4];
  const float* wa_b  = (const float*)d_in[5];
  const float* va    = (const float*)d_in[6];
  const float* b_ih0 = (const float*)d_in[9];
  const float* b_hh0 = (const float*)d_in[10];
  const float* b_ih1 = (const float*)d_in[13];
  const float* b_hh1 = (const float*)d_in[14];
  const float* out_W = (const float*)d_in[15];
  const float* out_b = (const float*)d_in[16];
  const float* W_ih0 = (const float*)d_in[7];
  const float* W_hh0 = (const float*)d_in[8];
  const float* W_ih1 = (const float*)d_in[11];
  const float* W_hh1 = (const float*)d_in[12];

  float* y_out  = (float*)d_out;
  float* h_out  = y_out + (size_t)T2N * BB * VV;
  float* ls_out = h_out + 2 * BB * HH;

  char* ws = (char*)d_ws;
  size_t off = 0;
  auto alloc = [&](size_t bytes) -> void* {
    void* p = ws + off;
    off += (bytes + 255) & ~(size_t)255;
    return p;
  };
  ushort* encB   = (ushort*)alloc((size_t)T1N * BB * HH * 2);
  ushort* ginB   = (ushort*)alloc((size_t)T2N * BB * 2 * HH * 2);
  ushort* WeB    = (ushort*)alloc((size_t)HH * HH * 2);
  ushort* WxB    = (ushort*)alloc((size_t)HH * HH * 2);
  ushort* Wih0B  = (ushort*)alloc((size_t)3 * HH * 2 * HH * 2);
  ushort* Whh0B  = (ushort*)alloc((size_t)3 * HH * HH * 2);
  ushort* Wih1B  = (ushort*)alloc((size_t)3 * HH * HH * 2);
  ushort* Whh1B  = (ushort*)alloc((size_t)3 * HH * HH * 2);
  ushort* outWB  = (ushort*)alloc((size_t)VV * HH * 2);
  ushort* stateB = (ushort*)alloc((size_t)BB * HH * 2);
  float* encproj = (float*)alloc((size_t)T1N * BB * HH * 4);
  float* xproj   = (float*)alloc((size_t)T2N * BB * HH * 4);
  float* eM      = (float*)alloc((size_t)T2N * BB * T1N * 4);
  float* score   = (float*)alloc((size_t)T2N * BB * T1N * 4);
  ushort* gi0B   = (ushort*)alloc((size_t)T2N * BB * 3 * HH * 2);
  ushort* gh0x   = (ushort*)alloc((size_t)BB * 3 * HH * 2);
  ushort* gh1buf0 = (ushort*)alloc((size_t)BB * 3 * HH * 2);
  ushort* gh1buf1 = (ushort*)alloc((size_t)BB * 3 * HH * 2);
  ushort* gi1x   = (ushort*)alloc((size_t)BB * 3 * HH * 2);
  float* h0buf0  = (float*)alloc((size_t)BB * HH * 4);
  float* h0buf1  = (float*)alloc((size_t)BB * HH * 4);
  float* h1buf0  = (float*)alloc((size_t)BB * HH * 4);
  float* h1buf1  = (float*)alloc((size_t)BB * HH * 4);
  ushort* h0bufB0 = (ushort*)alloc((size_t)BB * HH * 2);
  ushort* h0bufB1 = (ushort*)alloc((size_t)BB * HH * 2);
  ushort* ysB    = (ushort*)alloc((size_t)T2N * BB * HH * 2);
  unsigned* bar  = (unsigned*)alloc(2048);

  // preamble
  k_bar_init<<<1, 256, 0, stream>>>(bar);
  k_cvt<<<VV * HH / 1024, 256, 0, stream>>>(out_W, outWB, VV * HH);
  k_cvt<<<T1N * BB * HH / 1024, 256, 0, stream>>>(enc, encB, T1N * BB * HH);
  k_cvt<<<3 * HH * 2 * HH / 1024, 256, 0, stream>>>(W_ih0, Wih0B, 3 * HH * 2 * HH);
  k_cvt<<<3 * HH * HH / 1024, 256, 0, stream>>>(W_hh0, Whh0B, 3 * HH * HH);
  k_cvt<<<3 * HH * HH / 1024, 256, 0, stream>>>(W_ih1, Wih1B, 3 * HH * HH);
  k_cvt<<<3 * HH * HH / 1024, 256, 0, stream>>>(W_hh1, Whh1B, 3 * HH * HH);
  k_cvt<<<BB * HH / 1024, 256, 0, stream>>>(state, stateB, BB * HH);
  k_cvt_wa<<<2 * HH * HH / 1024, 256, 0, stream>>>(wa_W, WxB, WeB);
  k_embed<<<T2N * BB * HH / 1024, 256, 0, stream>>>(toks, emb, ginB);

  k_gemm<<<dim3(HH / 128, T1N * BB / 128), 256, 0, stream>>>(encB, HH, WeB, wa_b, encproj, HH, HH);
  k_gemm<<<dim3(HH / 128, T2N * BB / 128), 256, 0, stream>>>(ginB, 2 * HH, WxB, nullptr, xproj, HH, HH);

  k_scores<<<512, 256, 0, stream>>>(xproj, encproj, va, eM);
  k_softmax<<<T2N * BB, 128, 0, stream>>>(eM, score, ls_out);
  k_attv<<<256, 256, 0, stream>>>(enc, score, ginB);

  k_gemm_b16<<<dim3(3 * HH / 128, T2N * BB / 128), 256, 0, stream>>>(ginB, 2 * HH, Wih0B, b_ih0, gi0B, 3 * HH, 2 * HH);

  // recurrence: single persistent cooperative kernel, hierarchical XCD barrier
  RecurP rp;
  rp.Whh0B = Whh0B; rp.Whh1B = Whh1B; rp.Wih1B = Wih1B;
  rp.bhh0 = b_hh0; rp.bhh1 = b_hh1; rp.bih1 = b_ih1;
  rp.gi0B = gi0B;
  rp.state = state; rp.stateB = stateB;
  rp.gh0x = gh0x;
  rp.gh1b0 = gh1buf0; rp.gh1b1 = gh1buf1;
  rp.gi1x = gi1x;
  rp.h0b0 = h0buf0; rp.h0b1 = h0buf1;
  rp.h1b0 = h1buf0; rp.h1b1 = h1buf1;
  rp.h0B0 = h0bufB0; rp.h0B1 = h0bufB1;
  rp.h_out = h_out; rp.ysB = ysB;
  rp.bar = bar;
  void* kargs[] = { &rp };
  hipLaunchCooperativeKernel((const void*)k_recur, dim3(48), dim3(256), kargs, 0, stream);

  // y = ys @ out_W^T + out_b
  k_gemm<<<dim3(VV / 128, T2N * BB / 128), 256, 0, stream>>>(ysB, HH, outWB, out_b, y_out, VV, HH);
}